// Round 10
// baseline (207.764 us; speedup 1.0000x reference)
//
#include <hip/hip_runtime.h>
#include <hip/hip_bf16.h>
#include <math.h>

// ---------------------------------------------------------------------------
// SupConLoss on MI355X.
// out = 0.5*CE(predicts,targets) + 0.5*nt_xent(Anorm, temp=0.1)
//       + 0.25*nt_xent2(Anorm, temp=0.05)
// Round 10: single-wave 64x64 triangular tiles, register-direct MFMA with
// PRE-PACKED fragment layout (AITER-flatmm style).
//  - k_prep normalizes AND shuffles A into chunk[strip][kb][mt][lane] 16B
//    order, so every gemm fragment load is base+lane*16B: one coalesced
//    1 KB transaction (round 9's row-scatter cost ~16 transactions/load).
//  - No LDS, no barriers in gemm (labels via __shfl): compiler pipelines
//    loads across iterations with fine-grained vmcnt.
//  - k_merge and k_final fused via fence + atomic-counter last-block
//    pattern (device-scope) -> one fewer dispatch.
// Exp sums unshifted (|exponent|<=20, fp32-safe); reference row-max shift
// applied exactly in merge: S_j = s2_raw * exp(-20*vmax_j).
// ---------------------------------------------------------------------------

typedef __attribute__((ext_vector_type(8))) short bf16x8;
typedef __attribute__((ext_vector_type(4))) float f32x4;

__device__ __forceinline__ float blockReduceSum(float v, float* sbuf) {
#pragma unroll
  for (int o = 32; o > 0; o >>= 1) v += __shfl_down(v, o, 64);
  int lane = threadIdx.x & 63;
  int w = threadIdx.x >> 6;
  __syncthreads();
  if (lane == 0) sbuf[w] = v;
  __syncthreads();
  return sbuf[0] + sbuf[1] + sbuf[2] + sbuf[3];
}

// --- 1. fused normalize + fragment-pack (bf16) + per-row CE ----------------
// Packed layout: 16B chunk index = ((strip*KB + kb)*4 + mt)*64 + lane
//   holds row = strip*64 + mt*16 + (lane&15),
//   k = kb*32 + (lane>>4)*8 .. +7   (exactly one MFMA A/B fragment slice).
__global__ void k_prep(const float* __restrict__ X, const float* __restrict__ P,
                       const int* __restrict__ tgt, uint4* __restrict__ Pk,
                       float* __restrict__ ce_row, int D, int C) {
  __shared__ float sbuf[8];
  int row = blockIdx.x;
  const float* x = X + (size_t)row * D;
  float ss = 0.f;
  for (int j = threadIdx.x; j < D; j += blockDim.x) {
    float v = x[j];
    ss += v * v;
  }
  ss = blockReduceSum(ss, sbuf);
  float inv = 1.0f / fmaxf(sqrtf(ss), 1e-12f);

  const int KB = D / 32;           // 24
  const int strip = row >> 6;
  const int mt = (row >> 4) & 3;
  const int l4 = row & 15;
  const int nchunk = D / 8;        // 96
  for (int c = threadIdx.x; c < nchunk; c += blockDim.x) {
    int kb = c >> 2;
    int lsub = c & 3;
    int k0 = kb * 32 + lsub * 8;
    union { unsigned short u[8]; uint4 q; } pk;
#pragma unroll
    for (int j = 0; j < 8; ++j) {
      union { __hip_bfloat16 h; unsigned short us; } cv;
      cv.h = __float2bfloat16(x[k0 + j] * inv);
      pk.u[j] = cv.us;
    }
    int lane = l4 + 16 * lsub;
    size_t chunk = ((size_t)(strip * KB + kb) * 4 + mt) * 64 + lane;
    Pk[chunk] = pk.q;
  }
  if (threadIdx.x == 0) {
    const float* p = P + (size_t)row * C;
    float m = -INFINITY;
    for (int c = 0; c < C; ++c) m = fmaxf(m, p[c]);
    float s = 0.f;
    for (int c = 0; c < C; ++c) s += expf(p[c] - m);
    int t = tgt[row];
    ce_row[row] = -(p[t] - m - logf(s));
  }
}

// --- 2. single-wave 64x64 fused symmetric GEMM + stats, packed loads -------
// part layout: float4 part[N][NB]; (psum, s1_raw, s2_raw, m2=20*vmax_neg).
__global__ __launch_bounds__(64) void k_gemm_fused(
    const unsigned short* __restrict__ Pk, const int* __restrict__ lab,
    float4* __restrict__ part, int N, int K, int NB) {
  // triangular decode: bid -> (by, bx), by >= bx
  int bid = blockIdx.x;
  int by = (int)((sqrtf(8.f * (float)bid + 1.f) - 1.f) * 0.5f);
  while ((by + 1) * (by + 2) / 2 <= bid) ++by;
  while (by * (by + 1) / 2 > bid) --by;
  int bx = bid - by * (by + 1) / 2;

  const int t = threadIdx.x;  // == lane (single wave)
  const int rowBase = by * 64;
  const int colBase = bx * 64;
  const int KB = K / 32;

  const int myLR = lab[rowBase + t];
  const int myLC = lab[colBase + t];

  // per-kb fragment base (in shorts): ((strip*KB+kb)*4+mt)*64*8 + t*8
  const unsigned short* aP = Pk + ((size_t)by * KB * 4 * 64 + t) * 8;
  const unsigned short* bP = Pk + ((size_t)bx * KB * 4 * 64 + t) * 8;

  f32x4 acc[4][4] = {};
#pragma unroll 2
  for (int kb = 0; kb < KB; ++kb) {
    bf16x8 af[4], bf[4];
    const unsigned short* ak = aP + (size_t)kb * 4 * 512;  // 4 mt * 64 lanes * 8
    const unsigned short* bk = bP + (size_t)kb * 4 * 512;
#pragma unroll
    for (int mt = 0; mt < 4; ++mt) af[mt] = *(const bf16x8*)(ak + mt * 512);
#pragma unroll
    for (int nt = 0; nt < 4; ++nt) bf[nt] = *(const bf16x8*)(bk + nt * 512);
#pragma unroll
    for (int mt = 0; mt < 4; ++mt)
#pragma unroll
      for (int nt = 0; nt < 4; ++nt)
        acc[mt][nt] = __builtin_amdgcn_mfma_f32_16x16x32_bf16(
            af[mt], bf[nt], acc[mt][nt], 0, 0, 0);
  }

  // ---- fused single-pass epilogue ----------------------------------------
  // element: row = mt*16 + (t>>4)*4 + r ; col = nt*16 + (t&15)
  int cl[4];
#pragma unroll
  for (int nt = 0; nt < 4; ++nt) cl[nt] = __shfl(myLC, nt * 16 + (t & 15), 64);
  const bool dg = (by == bx);

  float bps[4] = {}, bs1[4] = {}, bs2[4] = {};
  float bvm[4] = {-1e30f, -1e30f, -1e30f, -1e30f};

#pragma unroll
  for (int mt = 0; mt < 4; ++mt) {
#pragma unroll
    for (int r = 0; r < 4; ++r) {
      int rowL = mt * 16 + (t >> 4) * 4 + r;
      int lr = __shfl(myLR, rowL, 64);
      float ps = 0.f, s1 = 0.f, s2 = 0.f, vm = -1e30f;
#pragma unroll
      for (int nt = 0; nt < 4; ++nt) {
        float v = acc[mt][nt][r];
        int colL = nt * 16 + (t & 15);
        bool diag = dg && (rowL == colL);
        bool same = (lr == cl[nt]);
        float e10 = __expf(v * 10.f);
        float e20 = e10 * e10;
        s1 += diag ? 1.f : e10;
        ps += (same && !diag) ? v : 0.f;
        s2 += same ? 0.f : e20;
        vm = same ? vm : fmaxf(vm, v);
        if (!dg) {  // B-side accumulation (consumed only off-diagonal)
          bs1[nt] += e10;
          bps[nt] += same ? v : 0.f;
          bs2[nt] += same ? 0.f : e20;
          bvm[nt] = same ? bvm[nt] : fmaxf(bvm[nt], v);
        }
      }
#pragma unroll
      for (int o = 1; o < 16; o <<= 1) {
        ps += __shfl_xor(ps, o, 64);
        s1 += __shfl_xor(s1, o, 64);
        s2 += __shfl_xor(s2, o, 64);
        vm = fmaxf(vm, __shfl_xor(vm, o, 64));
      }
      if ((t & 15) == 0)
        part[(size_t)(rowBase + rowL) * NB + bx] =
            make_float4(ps, s1, s2, 20.f * vm);
    }
  }

  if (!dg) {
#pragma unroll
    for (int nt = 0; nt < 4; ++nt) {
      float ps = bps[nt], s1 = bs1[nt], s2 = bs2[nt], vm = bvm[nt];
#pragma unroll
      for (int o = 16; o < 64; o <<= 1) {
        ps += __shfl_xor(ps, o, 64);
        s1 += __shfl_xor(s1, o, 64);
        s2 += __shfl_xor(s2, o, 64);
        vm = fmaxf(vm, __shfl_xor(vm, o, 64));
      }
      if ((t >> 4) == 0)
        part[(size_t)(colBase + nt * 16 + (t & 15)) * NB + by] =
            make_float4(ps, s1, s2, 20.f * vm);
    }
  }
}

// --- 3. merge partials per row + last-block finalize -----------------------
__global__ void k_merge_final(const float4* __restrict__ part,
                              const float* __restrict__ ce_row,
                              float* __restrict__ psumRow,
                              float* __restrict__ logS1,
                              float* __restrict__ Srow,
                              const int* __restrict__ lab,
                              float* __restrict__ out,
                              int* __restrict__ counter, int N, int NB,
                              int C) {
  int lane = threadIdx.x & 63;
  int w = threadIdx.x >> 6;
  int row = blockIdx.x * 4 + w;
  float ps = 0.f, s1 = 0.f, s2 = 0.f, m2 = -1e30f;
  if (lane < NB) {
    float4 p = part[(size_t)row * NB + lane];
    ps = p.x; s1 = p.y; s2 = p.z; m2 = p.w;
  }
#pragma unroll
  for (int o = 32; o > 0; o >>= 1) {
    ps += __shfl_down(ps, o, 64);
    s1 += __shfl_down(s1, o, 64);
    s2 += __shfl_down(s2, o, 64);
    m2 = fmaxf(m2, __shfl_down(m2, o, 64));
  }
  if (lane == 0) {
    psumRow[row] = ps;
    logS1[row] = logf(s1);
    Srow[row] = (m2 < -1e29f) ? 0.f : s2 * expf(-m2);
  }

  // last-block-finalize (device-scope release/acquire via counter)
  __threadfence();
  __shared__ int isLast;
  if (threadIdx.x == 0)
    isLast = (atomicAdd(counter, 1) == (int)gridDim.x - 1) ? 1 : 0;
  __syncthreads();
  if (!isLast) return;
  __threadfence();

  __shared__ float classS[32];
  __shared__ int classCnt[32];
  __shared__ float sbuf[8];
  if (threadIdx.x < 32) {
    classS[threadIdx.x] = 0.f;
    classCnt[threadIdx.x] = 0;
  }
  __syncthreads();
  float sumCe = 0.f;
  for (int i = threadIdx.x; i < N; i += blockDim.x) {
    sumCe += ce_row[i];
    int l = lab[i];
    atomicAdd(&classCnt[l], 1);
    atomicAdd(&classS[l], Srow[i]);
  }
  __syncthreads();
  float sumP1 = 0.f;
  for (int i = threadIdx.x; i < N; i += blockDim.x) {
    int l = lab[i];
    int pc = classCnt[l] - 1;
    if (pc > 0) sumP1 += psumRow[i] * 10.f / (float)pc - logS1[i];
  }
  sumCe = blockReduceSum(sumCe, sbuf);
  sumP1 = blockReduceSum(sumP1, sbuf);
  if (threadIdx.x == 0) {
    float totS = 0.f;
    for (int c = 0; c < C; ++c) totS += classS[c];
    float l2sum = 0.f;
    for (int c = 0; c < C; ++c) {
      int cnt = classCnt[c];
      if (cnt >= 2) {
        float negs = (float)(N - cnt);
        float x = (totS - classS[c]) / negs;
        l2sum += (float)cnt * logf(x + 1e-12f);
      }
    }
    float ce = sumCe / (float)N;
    float ntx1 = -sumP1 / (float)N;
    float ntx2 = l2sum / (float)N;
    out[0] = 0.5f * ce + 0.5f * ntx1 + 0.25f * ntx2;
  }
}

extern "C" void kernel_launch(void* const* d_in, const int* in_sizes, int n_in,
                              void* d_out, int out_size, void* d_ws,
                              size_t ws_size, hipStream_t stream) {
  const float* X = (const float*)d_in[0];  // cls_feats [N,D]
  const float* P = (const float*)d_in[1];  // predicts  [N,C]
  const int* tgt = (const int*)d_in[2];    // targets   [N]
  float* out = (float*)d_out;

  int N = in_sizes[2];
  int D = in_sizes[0] / N;
  int C = in_sizes[1] / N;
  int NB = N / 64;

  char* ws = (char*)d_ws;
  uint4* Pk = (uint4*)ws;                            // N*D bf16, packed
  float4* part = (float4*)(ws + (size_t)N * D * 2);  // N*NB float4
  float* ce_row = (float*)((char*)part + (size_t)N * NB * 16);
  float* psumRow = ce_row + N;
  float* logS1 = psumRow + N;
  float* Srow = logS1 + N;
  int* counter = (int*)(Srow + N);

  hipMemsetAsync(counter, 0, sizeof(int), stream);
  k_prep<<<N, 256, 0, stream>>>(X, P, tgt, Pk, ce_row, D, C);
  int nblk = NB * (NB + 1) / 2;
  k_gemm_fused<<<nblk, 64, 0, stream>>>((const unsigned short*)Pk, tgt, part,
                                        N, D, NB);
  k_merge_final<<<N / 4, 256, 0, stream>>>(part, ce_row, psumRow, logS1, Srow,
                                           tgt, out, counter, N, NB, C);
}

// Round 11
// 138.699 us; speedup vs baseline: 1.4979x; 1.4979x over previous
//
#include <hip/hip_runtime.h>
#include <hip/hip_bf16.h>
#include <math.h>

// ---------------------------------------------------------------------------
// SupConLoss on MI355X.
// out = 0.5*CE(predicts,targets) + 0.5*nt_xent(Anorm, temp=0.1)
//       + 0.25*nt_xent2(Anorm, temp=0.05)
// Round 11: round-10 packed-fragment register-direct gemm, but REVERTED to
// separate k_merge + k_final dispatches. Round 10's fused merge_final cost
// 91 us: per-block __threadfence() (device-scope release) forces L2
// writeback on every one of 1024 blocks on non-coherent-XCD hardware.
// Stream order is the cheap way to get cross-block visibility.
//  - k_prep packs A into chunk[strip][kb][mt][lane] 16B order: every gemm
//    fragment load is base+lane*16B, one coalesced 1 KB transaction.
//  - gemm: no LDS, no barriers; labels via __shfl; unroll 4 K-loop.
// Exp sums unshifted (|exponent|<=20, fp32-safe); reference row-max shift
// applied exactly in merge: S_j = s2_raw * exp(-20*vmax_j).
// ---------------------------------------------------------------------------

typedef __attribute__((ext_vector_type(8))) short bf16x8;
typedef __attribute__((ext_vector_type(4))) float f32x4;

__device__ __forceinline__ float blockReduceSum(float v, float* sbuf) {
#pragma unroll
  for (int o = 32; o > 0; o >>= 1) v += __shfl_down(v, o, 64);
  int lane = threadIdx.x & 63;
  int w = threadIdx.x >> 6;
  __syncthreads();
  if (lane == 0) sbuf[w] = v;
  __syncthreads();
  return sbuf[0] + sbuf[1] + sbuf[2] + sbuf[3];
}

// --- 1. fused normalize + fragment-pack (bf16) + per-row CE ----------------
// Packed layout: 16B chunk index = ((strip*KB + kb)*4 + mt)*64 + lane
//   holds row = strip*64 + mt*16 + (lane&15),
//   k = kb*32 + (lane>>4)*8 .. +7   (exactly one MFMA A/B fragment slice).
__global__ void k_prep(const float* __restrict__ X, const float* __restrict__ P,
                       const int* __restrict__ tgt, uint4* __restrict__ Pk,
                       float* __restrict__ ce_row, int D, int C) {
  __shared__ float sbuf[8];
  int row = blockIdx.x;
  const float* x = X + (size_t)row * D;
  float ss = 0.f;
  for (int j = threadIdx.x; j < D; j += blockDim.x) {
    float v = x[j];
    ss += v * v;
  }
  ss = blockReduceSum(ss, sbuf);
  float inv = 1.0f / fmaxf(sqrtf(ss), 1e-12f);

  const int KB = D / 32;           // 24
  const int strip = row >> 6;
  const int mt = (row >> 4) & 3;
  const int l4 = row & 15;
  const int nchunk = D / 8;        // 96
  for (int c = threadIdx.x; c < nchunk; c += blockDim.x) {
    int kb = c >> 2;
    int lsub = c & 3;
    int k0 = kb * 32 + lsub * 8;
    union { unsigned short u[8]; uint4 q; } pk;
#pragma unroll
    for (int j = 0; j < 8; ++j) {
      union { __hip_bfloat16 h; unsigned short us; } cv;
      cv.h = __float2bfloat16(x[k0 + j] * inv);
      pk.u[j] = cv.us;
    }
    int lane = l4 + 16 * lsub;
    size_t chunk = ((size_t)(strip * KB + kb) * 4 + mt) * 64 + lane;
    Pk[chunk] = pk.q;
  }
  if (threadIdx.x == 0) {
    const float* p = P + (size_t)row * C;
    float m = -INFINITY;
    for (int c = 0; c < C; ++c) m = fmaxf(m, p[c]);
    float s = 0.f;
    for (int c = 0; c < C; ++c) s += expf(p[c] - m);
    int t = tgt[row];
    ce_row[row] = -(p[t] - m - logf(s));
  }
}

// --- 2. single-wave 64x64 fused symmetric GEMM + stats, packed loads -------
// part layout: float4 part[N][NB]; (psum, s1_raw, s2_raw, m2=20*vmax_neg).
__global__ __launch_bounds__(64) void k_gemm_fused(
    const unsigned short* __restrict__ Pk, const int* __restrict__ lab,
    float4* __restrict__ part, int N, int K, int NB) {
  // triangular decode: bid -> (by, bx), by >= bx
  int bid = blockIdx.x;
  int by = (int)((sqrtf(8.f * (float)bid + 1.f) - 1.f) * 0.5f);
  while ((by + 1) * (by + 2) / 2 <= bid) ++by;
  while (by * (by + 1) / 2 > bid) --by;
  int bx = bid - by * (by + 1) / 2;

  const int t = threadIdx.x;  // == lane (single wave)
  const int rowBase = by * 64;
  const int colBase = bx * 64;
  const int KB = K / 32;

  const int myLR = lab[rowBase + t];
  const int myLC = lab[colBase + t];

  // per-kb fragment base (in shorts): ((strip*KB+kb)*4+mt)*64*8 + t*8
  const unsigned short* aP = Pk + ((size_t)by * KB * 4 * 64 + t) * 8;
  const unsigned short* bP = Pk + ((size_t)bx * KB * 4 * 64 + t) * 8;

  f32x4 acc[4][4] = {};
#pragma unroll 4
  for (int kb = 0; kb < KB; ++kb) {
    bf16x8 af[4], bf[4];
    const unsigned short* ak = aP + (size_t)kb * 4 * 512;  // 4 mt * 64 lanes * 8
    const unsigned short* bk = bP + (size_t)kb * 4 * 512;
#pragma unroll
    for (int mt = 0; mt < 4; ++mt) af[mt] = *(const bf16x8*)(ak + mt * 512);
#pragma unroll
    for (int nt = 0; nt < 4; ++nt) bf[nt] = *(const bf16x8*)(bk + nt * 512);
#pragma unroll
    for (int mt = 0; mt < 4; ++mt)
#pragma unroll
      for (int nt = 0; nt < 4; ++nt)
        acc[mt][nt] = __builtin_amdgcn_mfma_f32_16x16x32_bf16(
            af[mt], bf[nt], acc[mt][nt], 0, 0, 0);
  }

  // ---- fused single-pass epilogue ----------------------------------------
  // element: row = mt*16 + (t>>4)*4 + r ; col = nt*16 + (t&15)
  int cl[4];
#pragma unroll
  for (int nt = 0; nt < 4; ++nt) cl[nt] = __shfl(myLC, nt * 16 + (t & 15), 64);
  const bool dg = (by == bx);

  float bps[4] = {}, bs1[4] = {}, bs2[4] = {};
  float bvm[4] = {-1e30f, -1e30f, -1e30f, -1e30f};

#pragma unroll
  for (int mt = 0; mt < 4; ++mt) {
#pragma unroll
    for (int r = 0; r < 4; ++r) {
      int rowL = mt * 16 + (t >> 4) * 4 + r;
      int lr = __shfl(myLR, rowL, 64);
      float ps = 0.f, s1 = 0.f, s2 = 0.f, vm = -1e30f;
#pragma unroll
      for (int nt = 0; nt < 4; ++nt) {
        float v = acc[mt][nt][r];
        int colL = nt * 16 + (t & 15);
        bool diag = dg && (rowL == colL);
        bool same = (lr == cl[nt]);
        float e10 = __expf(v * 10.f);
        float e20 = e10 * e10;
        s1 += diag ? 1.f : e10;
        ps += (same && !diag) ? v : 0.f;
        s2 += same ? 0.f : e20;
        vm = same ? vm : fmaxf(vm, v);
        if (!dg) {  // B-side accumulation (consumed only off-diagonal)
          bs1[nt] += e10;
          bps[nt] += same ? v : 0.f;
          bs2[nt] += same ? 0.f : e20;
          bvm[nt] = same ? bvm[nt] : fmaxf(bvm[nt], v);
        }
      }
#pragma unroll
      for (int o = 1; o < 16; o <<= 1) {
        ps += __shfl_xor(ps, o, 64);
        s1 += __shfl_xor(s1, o, 64);
        s2 += __shfl_xor(s2, o, 64);
        vm = fmaxf(vm, __shfl_xor(vm, o, 64));
      }
      if ((t & 15) == 0)
        part[(size_t)(rowBase + rowL) * NB + bx] =
            make_float4(ps, s1, s2, 20.f * vm);
    }
  }

  if (!dg) {
#pragma unroll
    for (int nt = 0; nt < 4; ++nt) {
      float ps = bps[nt], s1 = bs1[nt], s2 = bs2[nt], vm = bvm[nt];
#pragma unroll
      for (int o = 16; o < 64; o <<= 1) {
        ps += __shfl_xor(ps, o, 64);
        s1 += __shfl_xor(s1, o, 64);
        s2 += __shfl_xor(s2, o, 64);
        vm = fmaxf(vm, __shfl_xor(vm, o, 64));
      }
      if ((t >> 4) == 0)
        part[(size_t)(colBase + nt * 16 + (t & 15)) * NB + by] =
            make_float4(ps, s1, s2, 20.f * vm);
    }
  }
}

// --- 3. merge partials per row (64 colblocks -> full-wave reduce) ----------
__global__ void k_merge(const float4* __restrict__ part,
                        float* __restrict__ psumRow,
                        float* __restrict__ logS1, float* __restrict__ Srow,
                        int N, int NB) {
  int lane = threadIdx.x & 63;
  int w = threadIdx.x >> 6;
  int row = blockIdx.x * 4 + w;
  float ps = 0.f, s1 = 0.f, s2 = 0.f, m2 = -1e30f;
  if (lane < NB) {
    float4 p = part[(size_t)row * NB + lane];
    ps = p.x; s1 = p.y; s2 = p.z; m2 = p.w;
  }
#pragma unroll
  for (int o = 32; o > 0; o >>= 1) {
    ps += __shfl_down(ps, o, 64);
    s1 += __shfl_down(s1, o, 64);
    s2 += __shfl_down(s2, o, 64);
    m2 = fmaxf(m2, __shfl_down(m2, o, 64));
  }
  if (lane == 0) {
    psumRow[row] = ps;
    logS1[row] = logf(s1);
    Srow[row] = (m2 < -1e29f) ? 0.f : s2 * expf(-m2);
  }
}

// --- 4. finalize ----------------------------------------------------------
__global__ void k_final(const float* __restrict__ ce_row,
                        const float* __restrict__ psumRow,
                        const float* __restrict__ logS1,
                        const float* __restrict__ Srow,
                        const int* __restrict__ lab, float* __restrict__ out,
                        int N, int C) {
  __shared__ float classS[32];
  __shared__ int classCnt[32];
  __shared__ float sbuf[8];
  if (threadIdx.x < 32) {
    classS[threadIdx.x] = 0.f;
    classCnt[threadIdx.x] = 0;
  }
  __syncthreads();
  float sumCe = 0.f;
  for (int i = threadIdx.x; i < N; i += blockDim.x) {
    sumCe += ce_row[i];
    int l = lab[i];
    atomicAdd(&classCnt[l], 1);
    atomicAdd(&classS[l], Srow[i]);
  }
  __syncthreads();
  float sumP1 = 0.f;
  for (int i = threadIdx.x; i < N; i += blockDim.x) {
    int l = lab[i];
    int pc = classCnt[l] - 1;
    if (pc > 0) sumP1 += psumRow[i] * 10.f / (float)pc - logS1[i];
  }
  sumCe = blockReduceSum(sumCe, sbuf);
  sumP1 = blockReduceSum(sumP1, sbuf);
  if (threadIdx.x == 0) {
    float totS = 0.f;
    for (int c = 0; c < C; ++c) totS += classS[c];
    float l2sum = 0.f;
    for (int c = 0; c < C; ++c) {
      int cnt = classCnt[c];
      if (cnt >= 2) {
        float negs = (float)(N - cnt);
        float x = (totS - classS[c]) / negs;
        l2sum += (float)cnt * logf(x + 1e-12f);
      }
    }
    float ce = sumCe / (float)N;
    float ntx1 = -sumP1 / (float)N;
    float ntx2 = l2sum / (float)N;
    out[0] = 0.5f * ce + 0.5f * ntx1 + 0.25f * ntx2;
  }
}

extern "C" void kernel_launch(void* const* d_in, const int* in_sizes, int n_in,
                              void* d_out, int out_size, void* d_ws,
                              size_t ws_size, hipStream_t stream) {
  const float* X = (const float*)d_in[0];  // cls_feats [N,D]
  const float* P = (const float*)d_in[1];  // predicts  [N,C]
  const int* tgt = (const int*)d_in[2];    // targets   [N]
  float* out = (float*)d_out;

  int N = in_sizes[2];
  int D = in_sizes[0] / N;
  int C = in_sizes[1] / N;
  int NB = N / 64;

  char* ws = (char*)d_ws;
  uint4* Pk = (uint4*)ws;                            // N*D bf16, packed
  float4* part = (float4*)(ws + (size_t)N * D * 2);  // N*NB float4
  float* ce_row = (float*)((char*)part + (size_t)N * NB * 16);
  float* psumRow = ce_row + N;
  float* logS1 = psumRow + N;
  float* Srow = logS1 + N;

  k_prep<<<N, 256, 0, stream>>>(X, P, tgt, Pk, ce_row, D, C);
  int nblk = NB * (NB + 1) / 2;
  k_gemm_fused<<<nblk, 64, 0, stream>>>((const unsigned short*)Pk, tgt, part,
                                        N, D, NB);
  k_merge<<<N / 4, 256, 0, stream>>>(part, psumRow, logS1, Srow, N, NB);
  k_final<<<1, 256, 0, stream>>>(ce_row, psumRow, logS1, Srow, tgt, out, N, C);
}

// Round 12
// 137.135 us; speedup vs baseline: 1.5150x; 1.0114x over previous
//
#include <hip/hip_runtime.h>
#include <hip/hip_bf16.h>
#include <math.h>

// ---------------------------------------------------------------------------
// SupConLoss on MI355X.
// out = 0.5*CE(predicts,targets) + 0.5*nt_xent(Anorm, temp=0.1)
//       + 0.25*nt_xent2(Anorm, temp=0.05)
// Round 12: round-11 packed-fragment register-direct gemm, operand in FP8
// (OCP e4m3) instead of bf16.
//  - 3.15 MB packed matrix fits every XCD's 4 MB L2 -> HBM stalls vanish.
//  - Fragment = 8B/lane (dwordx2): frag regs halve -> compiler has ~60 spare
//    VGPRs to pipeline 2 iterations of loads (round 11's 88-reg budget
//    couldn't hold even one prefetch iteration -> serial ~550cyc/iter stall).
//  - mfma_f32_16x16x32_fp8_fp8: same shape/count/C-layout as bf16 version.
//  - Precision: G error sigma ~0.0045 -> final scalar error ~0.01 << 0.14.
// Exp sums unshifted (|exponent|<=20, fp32-safe); reference row-max shift
// applied exactly in merge: S_j = s2_raw * exp(-20*vmax_j).
// ---------------------------------------------------------------------------

typedef __attribute__((ext_vector_type(4))) float f32x4;

__device__ __forceinline__ float blockReduceSum(float v, float* sbuf) {
#pragma unroll
  for (int o = 32; o > 0; o >>= 1) v += __shfl_down(v, o, 64);
  int lane = threadIdx.x & 63;
  int w = threadIdx.x >> 6;
  __syncthreads();
  if (lane == 0) sbuf[w] = v;
  __syncthreads();
  return sbuf[0] + sbuf[1] + sbuf[2] + sbuf[3];
}

// --- 1. fused normalize + fp8 fragment-pack + per-row CE -------------------
// Packed layout: 8B chunk index = ((strip*KB + kb)*4 + mt)*64 + lane
//   holds row = strip*64 + mt*16 + (lane&15),
//   k = kb*32 + (lane>>4)*8 .. +7   (one fp8 MFMA A/B fragment slice).
__global__ void k_prep(const float* __restrict__ X, const float* __restrict__ P,
                       const int* __restrict__ tgt, uint2* __restrict__ Pk,
                       float* __restrict__ ce_row, int D, int C) {
  __shared__ float sbuf[8];
  int row = blockIdx.x;
  const float* x = X + (size_t)row * D;
  float ss = 0.f;
  for (int j = threadIdx.x; j < D; j += blockDim.x) {
    float v = x[j];
    ss += v * v;
  }
  ss = blockReduceSum(ss, sbuf);
  float inv = 1.0f / fmaxf(sqrtf(ss), 1e-12f);

  const int KB = D / 32;           // 24
  const int strip = row >> 6;
  const int mt = (row >> 4) & 3;
  const int l4 = row & 15;
  const int nchunk = D / 8;        // 96
  for (int c = threadIdx.x; c < nchunk; c += blockDim.x) {
    int kb = c >> 2;
    int lsub = c & 3;
    int k0 = kb * 32 + lsub * 8;
    float v[8];
#pragma unroll
    for (int j = 0; j < 8; ++j) v[j] = x[k0 + j] * inv;
    unsigned int r0 = 0, r1 = 0;
    r0 = __builtin_amdgcn_cvt_pk_fp8_f32(v[0], v[1], r0, 0);
    r0 = __builtin_amdgcn_cvt_pk_fp8_f32(v[2], v[3], r0, 1);
    r1 = __builtin_amdgcn_cvt_pk_fp8_f32(v[4], v[5], r1, 0);
    r1 = __builtin_amdgcn_cvt_pk_fp8_f32(v[6], v[7], r1, 1);
    int lane = l4 + 16 * lsub;
    size_t chunk = ((size_t)(strip * KB + kb) * 4 + mt) * 64 + lane;
    Pk[chunk] = make_uint2(r0, r1);
  }
  if (threadIdx.x == 0) {
    const float* p = P + (size_t)row * C;
    float m = -INFINITY;
    for (int c = 0; c < C; ++c) m = fmaxf(m, p[c]);
    float s = 0.f;
    for (int c = 0; c < C; ++c) s += expf(p[c] - m);
    int t = tgt[row];
    ce_row[row] = -(p[t] - m - logf(s));
  }
}

// --- 2. single-wave 64x64 fused symmetric GEMM + stats, fp8 packed ---------
// part layout: float4 part[N][NB]; (psum, s1_raw, s2_raw, m2=20*vmax_neg).
__global__ __launch_bounds__(64) void k_gemm_fused(
    const unsigned char* __restrict__ Pk, const int* __restrict__ lab,
    float4* __restrict__ part, int N, int K, int NB) {
  // triangular decode: bid -> (by, bx), by >= bx
  int bid = blockIdx.x;
  int by = (int)((sqrtf(8.f * (float)bid + 1.f) - 1.f) * 0.5f);
  while ((by + 1) * (by + 2) / 2 <= bid) ++by;
  while (by * (by + 1) / 2 > bid) --by;
  int bx = bid - by * (by + 1) / 2;

  const int t = threadIdx.x;  // == lane (single wave)
  const int rowBase = by * 64;
  const int colBase = bx * 64;
  const int KB = K / 32;

  const int myLR = lab[rowBase + t];
  const int myLC = lab[colBase + t];

  // byte offsets: chunk = ((strip*KB+kb)*4+mt)*64 + lane, 8 bytes each
  const unsigned char* aP = Pk + ((size_t)by * KB * 4 * 64 + t) * 8;
  const unsigned char* bP = Pk + ((size_t)bx * KB * 4 * 64 + t) * 8;

  f32x4 acc[4][4] = {};
#pragma unroll 4
  for (int kb = 0; kb < KB; ++kb) {
    long long af[4], bf[4];
    const unsigned char* ak = aP + (size_t)kb * 2048;  // 4 mt * 64 lanes * 8B
    const unsigned char* bk = bP + (size_t)kb * 2048;
#pragma unroll
    for (int mt = 0; mt < 4; ++mt)
      af[mt] = *(const long long*)(ak + mt * 512);
#pragma unroll
    for (int nt = 0; nt < 4; ++nt)
      bf[nt] = *(const long long*)(bk + nt * 512);
#pragma unroll
    for (int mt = 0; mt < 4; ++mt)
#pragma unroll
      for (int nt = 0; nt < 4; ++nt)
        acc[mt][nt] = __builtin_amdgcn_mfma_f32_16x16x32_fp8_fp8(
            af[mt], bf[nt], acc[mt][nt], 0, 0, 0);
  }

  // ---- fused single-pass epilogue ----------------------------------------
  // element: row = mt*16 + (t>>4)*4 + r ; col = nt*16 + (t&15)
  int cl[4];
#pragma unroll
  for (int nt = 0; nt < 4; ++nt) cl[nt] = __shfl(myLC, nt * 16 + (t & 15), 64);
  const bool dg = (by == bx);

  float bps[4] = {}, bs1[4] = {}, bs2[4] = {};
  float bvm[4] = {-1e30f, -1e30f, -1e30f, -1e30f};

#pragma unroll
  for (int mt = 0; mt < 4; ++mt) {
#pragma unroll
    for (int r = 0; r < 4; ++r) {
      int rowL = mt * 16 + (t >> 4) * 4 + r;
      int lr = __shfl(myLR, rowL, 64);
      float ps = 0.f, s1 = 0.f, s2 = 0.f, vm = -1e30f;
#pragma unroll
      for (int nt = 0; nt < 4; ++nt) {
        float v = acc[mt][nt][r];
        int colL = nt * 16 + (t & 15);
        bool diag = dg && (rowL == colL);
        bool same = (lr == cl[nt]);
        float e10 = __expf(v * 10.f);
        float e20 = e10 * e10;
        s1 += diag ? 1.f : e10;
        ps += (same && !diag) ? v : 0.f;
        s2 += same ? 0.f : e20;
        vm = same ? vm : fmaxf(vm, v);
        if (!dg) {  // B-side accumulation (consumed only off-diagonal)
          bs1[nt] += e10;
          bps[nt] += same ? v : 0.f;
          bs2[nt] += same ? 0.f : e20;
          bvm[nt] = same ? bvm[nt] : fmaxf(bvm[nt], v);
        }
      }
#pragma unroll
      for (int o = 1; o < 16; o <<= 1) {
        ps += __shfl_xor(ps, o, 64);
        s1 += __shfl_xor(s1, o, 64);
        s2 += __shfl_xor(s2, o, 64);
        vm = fmaxf(vm, __shfl_xor(vm, o, 64));
      }
      if ((t & 15) == 0)
        part[(size_t)(rowBase + rowL) * NB + bx] =
            make_float4(ps, s1, s2, 20.f * vm);
    }
  }

  if (!dg) {
#pragma unroll
    for (int nt = 0; nt < 4; ++nt) {
      float ps = bps[nt], s1 = bs1[nt], s2 = bs2[nt], vm = bvm[nt];
#pragma unroll
      for (int o = 16; o < 64; o <<= 1) {
        ps += __shfl_xor(ps, o, 64);
        s1 += __shfl_xor(s1, o, 64);
        s2 += __shfl_xor(s2, o, 64);
        vm = fmaxf(vm, __shfl_xor(vm, o, 64));
      }
      if ((t >> 4) == 0)
        part[(size_t)(colBase + nt * 16 + (t & 15)) * NB + by] =
            make_float4(ps, s1, s2, 20.f * vm);
    }
  }
}

// --- 3. merge partials per row (64 colblocks -> full-wave reduce) ----------
__global__ void k_merge(const float4* __restrict__ part,
                        float* __restrict__ psumRow,
                        float* __restrict__ logS1, float* __restrict__ Srow,
                        int N, int NB) {
  int lane = threadIdx.x & 63;
  int w = threadIdx.x >> 6;
  int row = blockIdx.x * 4 + w;
  float ps = 0.f, s1 = 0.f, s2 = 0.f, m2 = -1e30f;
  if (lane < NB) {
    float4 p = part[(size_t)row * NB + lane];
    ps = p.x; s1 = p.y; s2 = p.z; m2 = p.w;
  }
#pragma unroll
  for (int o = 32; o > 0; o >>= 1) {
    ps += __shfl_down(ps, o, 64);
    s1 += __shfl_down(s1, o, 64);
    s2 += __shfl_down(s2, o, 64);
    m2 = fmaxf(m2, __shfl_down(m2, o, 64));
  }
  if (lane == 0) {
    psumRow[row] = ps;
    logS1[row] = logf(s1);
    Srow[row] = (m2 < -1e29f) ? 0.f : s2 * expf(-m2);
  }
}

// --- 4. finalize ----------------------------------------------------------
__global__ void k_final(const float* __restrict__ ce_row,
                        const float* __restrict__ psumRow,
                        const float* __restrict__ logS1,
                        const float* __restrict__ Srow,
                        const int* __restrict__ lab, float* __restrict__ out,
                        int N, int C) {
  __shared__ float classS[32];
  __shared__ int classCnt[32];
  __shared__ float sbuf[8];
  if (threadIdx.x < 32) {
    classS[threadIdx.x] = 0.f;
    classCnt[threadIdx.x] = 0;
  }
  __syncthreads();
  float sumCe = 0.f;
  for (int i = threadIdx.x; i < N; i += blockDim.x) {
    sumCe += ce_row[i];
    int l = lab[i];
    atomicAdd(&classCnt[l], 1);
    atomicAdd(&classS[l], Srow[i]);
  }
  __syncthreads();
  float sumP1 = 0.f;
  for (int i = threadIdx.x; i < N; i += blockDim.x) {
    int l = lab[i];
    int pc = classCnt[l] - 1;
    if (pc > 0) sumP1 += psumRow[i] * 10.f / (float)pc - logS1[i];
  }
  sumCe = blockReduceSum(sumCe, sbuf);
  sumP1 = blockReduceSum(sumP1, sbuf);
  if (threadIdx.x == 0) {
    float totS = 0.f;
    for (int c = 0; c < C; ++c) totS += classS[c];
    float l2sum = 0.f;
    for (int c = 0; c < C; ++c) {
      int cnt = classCnt[c];
      if (cnt >= 2) {
        float negs = (float)(N - cnt);
        float x = (totS - classS[c]) / negs;
        l2sum += (float)cnt * logf(x + 1e-12f);
      }
    }
    float ce = sumCe / (float)N;
    float ntx1 = -sumP1 / (float)N;
    float ntx2 = l2sum / (float)N;
    out[0] = 0.5f * ce + 0.5f * ntx1 + 0.25f * ntx2;
  }
}

extern "C" void kernel_launch(void* const* d_in, const int* in_sizes, int n_in,
                              void* d_out, int out_size, void* d_ws,
                              size_t ws_size, hipStream_t stream) {
  const float* X = (const float*)d_in[0];  // cls_feats [N,D]
  const float* P = (const float*)d_in[1];  // predicts  [N,C]
  const int* tgt = (const int*)d_in[2];    // targets   [N]
  float* out = (float*)d_out;

  int N = in_sizes[2];
  int D = in_sizes[0] / N;
  int C = in_sizes[1] / N;
  int NB = N / 64;

  char* ws = (char*)d_ws;
  uint2* Pk = (uint2*)ws;                        // N*D fp8 bytes, packed
  float4* part = (float4*)(ws + (size_t)N * D);  // N*NB float4
  float* ce_row = (float*)((char*)part + (size_t)N * NB * 16);
  float* psumRow = ce_row + N;
  float* logS1 = psumRow + N;
  float* Srow = logS1 + N;

  k_prep<<<N, 256, 0, stream>>>(X, P, tgt, Pk, ce_row, D, C);
  int nblk = NB * (NB + 1) / 2;
  k_gemm_fused<<<nblk, 64, 0, stream>>>((const unsigned char*)Pk, tgt, part,
                                        N, D, NB);
  k_merge<<<N / 4, 256, 0, stream>>>(part, psumRow, logS1, Srow, N, NB);
  k_final<<<1, 256, 0, stream>>>(ce_row, psumRow, logS1, Srow, tgt, out, N, C);
}